// Round 14
// baseline (82.258 us; speedup 1.0000x reference)
//
#include <hip/hip_runtime.h>
#include <math.h>

#define BROWS 8192
#define F 10
#define NT 16                   // tiles (each wave: one 32-j block per tile)
#define NW 16                   // waves per block (1024 threads)
#define IB 16                   // i-rows per block
#define SQRT_LOG2E 1.2011224087864498f   // sqrt(log2(e)); q is prescaled so a1*b1 carries log2e once

#if __has_builtin(__builtin_amdgcn_exp2f)
#define EXP2F(x) __builtin_amdgcn_exp2f(x)
#else
#define EXP2F(x) exp2f(x)
#endif

typedef _Float16 half4 __attribute__((ext_vector_type(4)));
typedef __fp16 fp16x2 __attribute__((ext_vector_type(2)));
typedef float floatx4 __attribute__((ext_vector_type(4)));

__device__ __forceinline__ half4 exp4_to_h4(float a, float b, float c, float d) {
#if __has_builtin(__builtin_amdgcn_cvt_pkrtz)
    union { fp16x2 h2[2]; half4 h4; } u;
    u.h2[0] = __builtin_amdgcn_cvt_pkrtz(EXP2F(a), EXP2F(b));
    u.h2[1] = __builtin_amdgcn_cvt_pkrtz(EXP2F(c), EXP2F(d));
    return u.h4;
#else
    half4 r;
    r[0] = (_Float16)EXP2F(a); r[1] = (_Float16)EXP2F(b);
    r[2] = (_Float16)EXP2F(c); r[3] = (_Float16)EXP2F(d);
    return r;
#endif
}

__device__ __forceinline__ uint32_t pack2(_Float16 a, _Float16 b) {
    union { _Float16 h[2]; uint32_t u; } x;
    x.h[0] = a; x.h[1] = b;
    return x.u;
}

// async global->LDS DMA, 16B/lane; lds addr = wave-uniform base + lane*16.
__device__ __forceinline__ void gload_lds16(const void* g, void* l) {
#if __has_builtin(__builtin_amdgcn_global_load_lds)
    __builtin_amdgcn_global_load_lds(
        (const __attribute__((address_space(1))) void*)g,
        (__attribute__((address_space(3))) void*)l, 16, 0, 0);
#else
    *(float4*)l = *(const float4*)g;
#endif
}

__device__ __forceinline__ void wait_vm0() {
#if __has_builtin(__builtin_amdgcn_s_waitcnt)
    __builtin_amdgcn_s_waitcnt(0x0F70);   // vmcnt(0), lgkm/exp ignored
#endif
}

__device__ __forceinline__ void sched_fence() {
#if __has_builtin(__builtin_amdgcn_sched_barrier)
    __builtin_amdgcn_sched_barrier(0);    // pin: nothing crosses
#endif
}

// ---------------------------------------------------------------------------
// Kernel 1: pooled in TWO wave-private-tiled f16 layouts.
//   q_tiled[j][0..15]  (= [jblk][32][16]): feats 0..9 scaled by sqrt(log2e),
//     10..15 = 0. One 32-j block = 1024 B = one wave DMA. Feeds a1 AND b1.
//   a_tiled[jblk][n][32], n=0..15: rows 0..9 = pooled^T (unscaled), row 10 =
//     ONES (softmax denominator), 11..15 = 0. One block = 1024 B = one DMA.
// ---------------------------------------------------------------------------
__global__ void pooled_kernel(const float* __restrict__ x,
                              const float* __restrict__ A,
                              const float* __restrict__ W,
                              _Float16* __restrict__ q_tiled,
                              _Float16* __restrict__ a_tiled) {
    int b = blockIdx.x * blockDim.x + threadIdx.x;
    if (b >= BROWS) return;

    float c0 = 0.125f * (1.0f + A[0] + A[3]);
    float c1 = 0.125f * (1.0f + A[1] + A[4]);
    float c2 = 0.125f * (2.0f + A[2] + A[5]);

    const float2* xb = (const float2*)(x + (size_t)b * 3 * F);
    float xv[3 * F];
#pragma unroll
    for (int k = 0; k < 15; ++k) {
        float2 t = xb[k];
        xv[2 * k] = t.x; xv[2 * k + 1] = t.y;
    }

    float y[F];
#pragma unroll
    for (int f = 0; f < F; ++f)
        y[f] = c0 * xv[f] + c1 * xv[F + f] + c2 * xv[2 * F + f];

    float po[F];
#pragma unroll
    for (int o = 0; o < F; ++o) {
        float acc = 0.0f;
#pragma unroll
        for (int f = 0; f < F; ++f)
            acc = fmaf(y[f], W[f * F + o], acc);
        po[o] = acc;
    }

    // q_tiled row: 16 f16 = 32 B, scaled
    float s = SQRT_LOG2E;
    uint2* qd = (uint2*)(q_tiled + (size_t)b * 16);
    qd[0] = make_uint2(pack2((_Float16)(s*po[0]), (_Float16)(s*po[1])),
                       pack2((_Float16)(s*po[2]), (_Float16)(s*po[3])));
    qd[1] = make_uint2(pack2((_Float16)(s*po[4]), (_Float16)(s*po[5])),
                       pack2((_Float16)(s*po[6]), (_Float16)(s*po[7])));
    qd[2] = make_uint2(pack2((_Float16)(s*po[8]), (_Float16)(s*po[9])), 0u);
    qd[3] = make_uint2(0u, 0u);

    // a_tiled: [jblk][16][32]
    _Float16* at = a_tiled + (size_t)(b >> 5) * 512 + (b & 31);
#pragma unroll
    for (int o = 0; o < F; ++o)
        at[o * 32] = (_Float16)po[o];
    at[10 * 32] = (_Float16)1.0f;
#pragma unroll
    for (int o = 11; o < 16; ++o)
        at[o * 32] = (_Float16)0.0f;
}

// ---------------------------------------------------------------------------
// Kernel 2: MFMA flash attention with FULLY WAVE-PRIVATE staging — zero
// K-loop barriers. R13 lesson: occupancy didn't move the needle; R12 counters
// put the residual in the per-tile all-wave barrier+vmcnt(0) rendezvous on the
// shared abuf. Here wave w's tile t is j-block g=t*16+w; its q (32x16) and a
// (16x32) slabs are contiguous 1024 B each -> 2 private DMAs into a private
// 2 KB ring slot (depth 2). Inner loop: wait vmcnt(0) (only own slot's DMAs
// outstanding) -> 4 ds_read_b64 -> sched fence -> prefetch next slot -> MFMA.
//   MFMA1 (swapped): D1 = qj-frag * qi-frag -> S^T, C-layout == B-layout
//   exp2 -> f16 -> MFMA2: acc += a_tiled-frag * expS  (V^T, row 10 = l)
// LDS 64 KB -> 2 blocks/CU, 8 waves/SIMD. One barrier pair at the epilogue.
// ---------------------------------------------------------------------------
__global__ void attn_kernel(const _Float16* __restrict__ q_tiled,
                            const _Float16* __restrict__ a_tiled,
                            float* __restrict__ out) {
    __shared__ __align__(16) _Float16 ring[2][NW][1024];   // 2 KB/wave/slot = 64 KB
    float* red = (float*)&ring[0][0][0];                    // 12288 B, after final barrier

    const int tid  = threadIdx.x;
    const int wave = tid >> 6;          // 0..15
    const int lane = tid & 63;
    const int m    = lane & 15;
    const int quad = lane >> 4;
    const int i0   = blockIdx.x * IB;

    // B1 fragment: direct load (q_tiled is prescaled; cols 10..15 are zero)
    half4 b1 = *(const half4*)(q_tiled + (size_t)(i0 + m) * 16 + quad * 4);

    // rolling private DMA sources: j-block g = t*16 + wave
    const char* qsrc = (const char*)q_tiled + (size_t)wave * 1024 + lane * 16;
    const char* asrc = (const char*)a_tiled + (size_t)wave * 1024 + lane * 16;

    char* slot[2] = { (char*)&ring[0][wave][0] + lane * 16,
                      (char*)&ring[1][wave][0] + lane * 16 };

    floatx4 acc0 = {0.f,0.f,0.f,0.f}, acc1 = {0.f,0.f,0.f,0.f};

    // prologue: stage tile 0 into slot 0 (q at +0, a at +512 f16)
    gload_lds16(qsrc, slot[0]);
    gload_lds16(asrc + 0x40000 /*a_tiled is a separate ptr; offset unused*/ - 0x40000, slot[0] + 1024);
    qsrc += 16 * 1024; asrc += 16 * 1024;

    for (int t = 0; t < NT; ++t) {
        const int buf = t & 1;
        const _Float16* qs = &ring[buf][wave][0];
        const _Float16* as_ = qs + 512;

        wait_vm0();   // drains this slot's 2 DMAs (the only outstanding vmem)
        half4 a1_0 = *(const half4*)&qs[(0 * 16 + m) * 16 + quad * 4];
        half4 ag_0 = *(const half4*)&as_[m * 32 + 0 * 16 + quad * 4];
        half4 a1_1 = *(const half4*)&qs[(1 * 16 + m) * 16 + quad * 4];
        half4 ag_1 = *(const half4*)&as_[m * 32 + 1 * 16 + quad * 4];
        sched_fence();   // keep the prefetch below AFTER the reads above

        if (t + 1 < NT) {   // prefetch next tile into the other slot
            gload_lds16(qsrc, slot[buf ^ 1]);
            gload_lds16(asrc, slot[buf ^ 1] + 1024);
            qsrc += 16 * 1024; asrc += 16 * 1024;
        }

        floatx4 d1a = __builtin_amdgcn_mfma_f32_16x16x16f16(
            a1_0, b1, (floatx4){0.f,0.f,0.f,0.f}, 0, 0, 0);
        floatx4 d1b = __builtin_amdgcn_mfma_f32_16x16x16f16(
            a1_1, b1, (floatx4){0.f,0.f,0.f,0.f}, 0, 0, 0);
        half4 a2a = exp4_to_h4(d1a[0], d1a[1], d1a[2], d1a[3]);
        half4 a2b = exp4_to_h4(d1b[0], d1b[1], d1b[2], d1b[3]);
        acc0 = __builtin_amdgcn_mfma_f32_16x16x16f16(ag_0, a2a, acc0, 0, 0, 0);
        acc1 = __builtin_amdgcn_mfma_f32_16x16x16f16(ag_1, a2b, acc1, 0, 0, 0);
    }

    floatx4 acc = acc0 + acc1;   // lane: V^T[f=quad*4+r][i=i0+m], f=10 -> l

    __syncthreads();   // all waves done with their ring slots (red aliases ring)
    if (quad < 3)
        *(floatx4*)&red[((size_t)wave * IB + m) * 12 + quad * 4] = acc;
    __syncthreads();

    if (tid < IB * F) {
        const int i = tid / F;      // 0..15
        const int f = tid % F;
        float sum = 0.0f, l = 0.0f;
#pragma unroll
        for (int w = 0; w < NW; ++w) {
            sum += red[((size_t)w * IB + i) * 12 + f];
            l   += red[((size_t)w * IB + i) * 12 + 10];
        }
        out[(size_t)(i0 + i) * F + f] = sum / l;
    }
}

// ---------------------------------------------------------------------------
extern "C" void kernel_launch(void* const* d_in, const int* in_sizes, int n_in,
                              void* d_out, int out_size, void* d_ws, size_t ws_size,
                              hipStream_t stream) {
    const float* x = (const float*)d_in[0];   // [8192,3,10]
    const float* A = (const float*)d_in[1];   // [3,3]
    const float* W = (const float*)d_in[2];   // [10,10]
    float* out = (float*)d_out;               // [8192,10]

    _Float16* q_tiled = (_Float16*)d_ws;                      // 8192*16*2 = 262144 B
    _Float16* a_tiled = (_Float16*)((char*)d_ws + 262144);    // 256*512*2 = 262144 B

    pooled_kernel<<<BROWS / 64, 64, 0, stream>>>(x, A, W, q_tiled, a_tiled);
    attn_kernel<<<BROWS / IB, NW * 64, 0, stream>>>(q_tiled, a_tiled, out);
}

// Round 15
// 69.133 us; speedup vs baseline: 1.1899x; 1.1899x over previous
//
#include <hip/hip_runtime.h>
#include <math.h>

#define BROWS 8192
#define F 10
#define NT 16                   // tiles; wave w's tile t = j-block t*16+w (32 j-rows)
#define NW 16                   // waves per block (1024 threads)
#define IB 32                   // i-rows per block (two 16-row MFMA groups)
#define SQRT_LOG2E 1.2011224087864498f   // q prescaled so a1*b1 carries log2e once

#if __has_builtin(__builtin_amdgcn_exp2f)
#define EXP2F(x) __builtin_amdgcn_exp2f(x)
#else
#define EXP2F(x) exp2f(x)
#endif

// s_waitcnt imm: vmcnt[3:0] | expcnt(7, no-wait)<<4 | lgkmcnt(15, no-wait)<<8
#define WAITVM(n) __builtin_amdgcn_s_waitcnt(0xF00 | 0x70 | (n))

typedef _Float16 half4 __attribute__((ext_vector_type(4)));
typedef __fp16 fp16x2 __attribute__((ext_vector_type(2)));
typedef float floatx4 __attribute__((ext_vector_type(4)));

__device__ __forceinline__ half4 exp4_to_h4(float a, float b, float c, float d) {
#if __has_builtin(__builtin_amdgcn_cvt_pkrtz)
    union { fp16x2 h2[2]; half4 h4; } u;
    u.h2[0] = __builtin_amdgcn_cvt_pkrtz(EXP2F(a), EXP2F(b));
    u.h2[1] = __builtin_amdgcn_cvt_pkrtz(EXP2F(c), EXP2F(d));
    return u.h4;
#else
    half4 r;
    r[0] = (_Float16)EXP2F(a); r[1] = (_Float16)EXP2F(b);
    r[2] = (_Float16)EXP2F(c); r[3] = (_Float16)EXP2F(d);
    return r;
#endif
}

__device__ __forceinline__ uint32_t pack2(_Float16 a, _Float16 b) {
    union { _Float16 h[2]; uint32_t u; } x;
    x.h[0] = a; x.h[1] = b;
    return x.u;
}

// async global->LDS DMA, 16B/lane; lds addr = wave-uniform base + lane*16.
__device__ __forceinline__ void gload_lds16(const void* g, void* l) {
#if __has_builtin(__builtin_amdgcn_global_load_lds)
    __builtin_amdgcn_global_load_lds(
        (const __attribute__((address_space(1))) void*)g,
        (__attribute__((address_space(3))) void*)l, 16, 0, 0);
#else
    *(float4*)l = *(const float4*)g;
#endif
}

// ---------------------------------------------------------------------------
// Kernel 1: pooled in TWO wave-private-tiled f16 layouts (R14, correctness-
// proven):
//   q_tiled[j][0..15]: feats 0..9 scaled by sqrt(log2e), 10..15 = 0.
//     One 32-j block = 1024 B = one wave DMA. Feeds a1 AND b1.
//   a_tiled[jblk][n][32], n=0..15: rows 0..9 = pooled^T (unscaled),
//     row 10 = ONES (softmax denominator), 11..15 = 0. 1024 B per block.
// ---------------------------------------------------------------------------
__global__ void pooled_kernel(const float* __restrict__ x,
                              const float* __restrict__ A,
                              const float* __restrict__ W,
                              _Float16* __restrict__ q_tiled,
                              _Float16* __restrict__ a_tiled) {
    int b = blockIdx.x * blockDim.x + threadIdx.x;
    if (b >= BROWS) return;

    float c0 = 0.125f * (1.0f + A[0] + A[3]);
    float c1 = 0.125f * (1.0f + A[1] + A[4]);
    float c2 = 0.125f * (2.0f + A[2] + A[5]);

    const float2* xb = (const float2*)(x + (size_t)b * 3 * F);
    float xv[3 * F];
#pragma unroll
    for (int k = 0; k < 15; ++k) {
        float2 t = xb[k];
        xv[2 * k] = t.x; xv[2 * k + 1] = t.y;
    }

    float y[F];
#pragma unroll
    for (int f = 0; f < F; ++f)
        y[f] = c0 * xv[f] + c1 * xv[F + f] + c2 * xv[2 * F + f];

    float po[F];
#pragma unroll
    for (int o = 0; o < F; ++o) {
        float acc = 0.0f;
#pragma unroll
        for (int f = 0; f < F; ++f)
            acc = fmaf(y[f], W[f * F + o], acc);
        po[o] = acc;
    }

    float s = SQRT_LOG2E;
    uint2* qd = (uint2*)(q_tiled + (size_t)b * 16);
    qd[0] = make_uint2(pack2((_Float16)(s*po[0]), (_Float16)(s*po[1])),
                       pack2((_Float16)(s*po[2]), (_Float16)(s*po[3])));
    qd[1] = make_uint2(pack2((_Float16)(s*po[4]), (_Float16)(s*po[5])),
                       pack2((_Float16)(s*po[6]), (_Float16)(s*po[7])));
    qd[2] = make_uint2(pack2((_Float16)(s*po[8]), (_Float16)(s*po[9])), 0u);
    qd[3] = make_uint2(0u, 0u);

    _Float16* at = a_tiled + (size_t)(b >> 5) * 512 + (b & 31);
#pragma unroll
    for (int o = 0; o < F; ++o)
        at[o * 32] = (_Float16)po[o];
    at[10 * 32] = (_Float16)1.0f;
#pragma unroll
    for (int o = 11; o < 16; ++o)
        at[o * 32] = (_Float16)0.0f;
}

// ---------------------------------------------------------------------------
// Kernel 2: MFMA flash attention, wave-private DEPTH-4 ring, graduated
// vmcnt waits, ZERO K-loop barriers.
// R14 failed on pipeline depth (2-deep + vmcnt(0) + sched_barrier exposed
// L2 latency every tile). Here: prologue issues slots 0..2 (6 DMAs); each
// iter waits vmcnt(4) — drains ONLY the oldest slot's pair, keeps 4 loads
// in flight (AITER-style never-zero steady state; m135 oldest-first
// semantics make reorder of the prefetch around the wait counting-safe) —
// then 4 ds_read_b64, prefetch slot t+3, 4 MFMA1 + 16 exp2 + 4 MFMA2.
// Peeled tails use vmcnt(2)/vmcnt(0). 256 blocks x 1024 thr, IB=32:
// LDS = 4 slots x 16 waves x 2 KB = 128 KB -> 1 block/CU, 4 waves/SIMD
// (R13 showed 8 waves/SIMD is not the lever).
//   MFMA1 (swapped): D1 = qj-frag * qi-frag -> S^T, C-layout == B-layout
//   exp2 -> f16 -> MFMA2: acc += a_tiled-frag * expS  (V^T, row 10 = l)
// ---------------------------------------------------------------------------
__global__ void attn_kernel(const _Float16* __restrict__ q_tiled,
                            const _Float16* __restrict__ a_tiled,
                            float* __restrict__ out) {
    __shared__ __align__(16) _Float16 ring[4][NW][1024];   // 4 x 16 x 2 KB = 128 KB
    float* red = (float*)&ring[0][0][0];                   // 24576 B, after final barrier

    const int tid  = threadIdx.x;
    const int wave = tid >> 6;          // 0..15
    const int lane = tid & 63;
    const int m    = lane & 15;
    const int quad = lane >> 4;
    const int i0   = blockIdx.x * IB;

    // B1 fragments for the two i-groups (q_tiled prescaled; cols 10..15 zero)
    half4 b1a = *(const half4*)(q_tiled + (size_t)(i0 + m) * 16 + quad * 4);
    half4 b1b = *(const half4*)(q_tiled + (size_t)(i0 + 16 + m) * 16 + quad * 4);

    // rolling private DMA sources: j-block g = t*16 + wave, 16 KB/tile stride
    const char* qsrc = (const char*)q_tiled + (size_t)wave * 1024 + lane * 16;
    const char* asrc = (const char*)a_tiled + (size_t)wave * 1024 + lane * 16;

    char* slotp[4];
#pragma unroll
    for (int s = 0; s < 4; ++s)
        slotp[s] = (char*)&ring[s][wave][0] + lane * 16;

    // prologue: stage tiles 0..2 into slots 0..2 (q at +0, a at +1024 B)
#pragma unroll
    for (int s = 0; s < 3; ++s) {
        gload_lds16(qsrc, slotp[s]);
        gload_lds16(asrc, slotp[s] + 1024);
        qsrc += 16 * 1024; asrc += 16 * 1024;
    }

    floatx4 accA0 = {0.f,0.f,0.f,0.f}, accA1 = {0.f,0.f,0.f,0.f};
    floatx4 accB0 = {0.f,0.f,0.f,0.f}, accB1 = {0.f,0.f,0.f,0.f};

    for (int t = 0; t < NT; ++t) {
        // graduated wait: drain only the oldest slot's 2 loads
        if (t < NT - 2)      WAITVM(4);
        else if (t == NT-2)  WAITVM(2);
        else                 WAITVM(0);

        const _Float16* qs  = &ring[t & 3][wave][0];
        const _Float16* as_ = qs + 512;
        half4 a1_0 = *(const half4*)&qs[(0 * 16 + m) * 16 + quad * 4];
        half4 a1_1 = *(const half4*)&qs[(1 * 16 + m) * 16 + quad * 4];
        half4 ag_0 = *(const half4*)&as_[m * 32 + 0 * 16 + quad * 4];
        half4 ag_1 = *(const half4*)&as_[m * 32 + 1 * 16 + quad * 4];

        if (t + 3 < NT) {   // prefetch 3 tiles ahead into the freed slot
            gload_lds16(qsrc, slotp[(t + 3) & 3]);
            gload_lds16(asrc, slotp[(t + 3) & 3] + 1024);
            qsrc += 16 * 1024; asrc += 16 * 1024;
        }

        floatx4 z = {0.f,0.f,0.f,0.f};
        floatx4 d1a0 = __builtin_amdgcn_mfma_f32_16x16x16f16(a1_0, b1a, z, 0, 0, 0);
        floatx4 d1b0 = __builtin_amdgcn_mfma_f32_16x16x16f16(a1_0, b1b, z, 0, 0, 0);
        floatx4 d1a1 = __builtin_amdgcn_mfma_f32_16x16x16f16(a1_1, b1a, z, 0, 0, 0);
        floatx4 d1b1 = __builtin_amdgcn_mfma_f32_16x16x16f16(a1_1, b1b, z, 0, 0, 0);
        half4 a2a0 = exp4_to_h4(d1a0[0], d1a0[1], d1a0[2], d1a0[3]);
        half4 a2b0 = exp4_to_h4(d1b0[0], d1b0[1], d1b0[2], d1b0[3]);
        half4 a2a1 = exp4_to_h4(d1a1[0], d1a1[1], d1a1[2], d1a1[3]);
        half4 a2b1 = exp4_to_h4(d1b1[0], d1b1[1], d1b1[2], d1b1[3]);
        accA0 = __builtin_amdgcn_mfma_f32_16x16x16f16(ag_0, a2a0, accA0, 0, 0, 0);
        accB0 = __builtin_amdgcn_mfma_f32_16x16x16f16(ag_0, a2b0, accB0, 0, 0, 0);
        accA1 = __builtin_amdgcn_mfma_f32_16x16x16f16(ag_1, a2a1, accA1, 0, 0, 0);
        accB1 = __builtin_amdgcn_mfma_f32_16x16x16f16(ag_1, a2b1, accB1, 0, 0, 0);
    }

    floatx4 accA = accA0 + accA1;   // V^T[f=quad*4+r][i=i0+m],    f=10 -> l
    floatx4 accB = accB0 + accB1;   // V^T[f=quad*4+r][i=i0+16+m]

    __syncthreads();   // all waves done with ring (red aliases it)
    if (quad < 3) {
        *(floatx4*)&red[((size_t)wave * IB + m) * 12 + quad * 4] = accA;
        *(floatx4*)&red[((size_t)wave * IB + 16 + m) * 12 + quad * 4] = accB;
    }
    __syncthreads();

    if (tid < IB * F) {
        const int i = tid / F;      // 0..31
        const int f = tid % F;
        float sum = 0.0f, l = 0.0f;
#pragma unroll
        for (int w = 0; w < NW; ++w) {
            sum += red[((size_t)w * IB + i) * 12 + f];
            l   += red[((size_t)w * IB + i) * 12 + 10];
        }
        out[(size_t)(i0 + i) * F + f] = sum / l;
    }
}

// ---------------------------------------------------------------------------
extern "C" void kernel_launch(void* const* d_in, const int* in_sizes, int n_in,
                              void* d_out, int out_size, void* d_ws, size_t ws_size,
                              hipStream_t stream) {
    const float* x = (const float*)d_in[0];   // [8192,3,10]
    const float* A = (const float*)d_in[1];   // [3,3]
    const float* W = (const float*)d_in[2];   // [10,10]
    float* out = (float*)d_out;               // [8192,10]

    _Float16* q_tiled = (_Float16*)d_ws;                      // 8192*16*2 = 262144 B
    _Float16* a_tiled = (_Float16*)((char*)d_ws + 262144);    // 256*512*2 = 262144 B

    pooled_kernel<<<BROWS / 64, 64, 0, stream>>>(x, A, W, q_tiled, a_tiled);
    attn_kernel<<<BROWS / IB, NW * 64, 0, stream>>>(q_tiled, a_tiled, out);
}